// Round 14
// baseline (436.952 us; speedup 1.0000x reference)
//
#include <hip/hip_runtime.h>
#include <hip/hip_bf16.h>

// ---- problem constants ----
#define BB    16
#define TT    1024
#define MTOK  (BB*TT)     // 16384 tokens
#define IDIM_ 345
#define KPAD  384         // padded to /64 for BK=64
#define LL    4
#define DD_   256
#define FF_   1024
#define EPS_  1e-5f
#define QSCL  0.18033688f   // 0.125 * log2(e)
#define MSHIFT 12.0f        // fixed softmax shift (scores are O(1) in log2 units)

typedef __bf16 bf16;
typedef bf16 bf16x8 __attribute__((ext_vector_type(8)));
typedef float f32x4 __attribute__((ext_vector_type(4)));

static __device__ __forceinline__ f32x4 MFMA(bf16x8 a, bf16x8 b, f32x4 c) {
  return __builtin_amdgcn_mfma_f32_16x16x32_bf16(a, b, c, 0, 0, 0);
}
static __device__ __forceinline__ unsigned bfbits(float x) {
  return (unsigned)__builtin_bit_cast(unsigned short, (bf16)x);
}
static __device__ __forceinline__ bf16x8 ld_bf8(const void* p) {
  return *reinterpret_cast<const bf16x8*>(p);
}
static __device__ __forceinline__ void gload_lds16(const bf16* g, void* l) {
  __builtin_amdgcn_global_load_lds(
      (const __attribute__((address_space(1))) void*)g,
      (__attribute__((address_space(3))) void*)l, 16, 0, 0);
}

// ---- conversion kernels ----
__global__ void k_convert_pad(const float* __restrict__ src, bf16* __restrict__ dst) {
  int idx = blockIdx.x * 256 + threadIdx.x;          // quad index
  if (idx >= MTOK * (KPAD / 4)) return;
  int r = idx / (KPAD / 4), c0 = (idx % (KPAD / 4)) * 4;
  const float* s = src + (long)r * IDIM_ + c0;
  float v0 = (c0 + 0 < IDIM_) ? s[0] : 0.f;
  float v1 = (c0 + 1 < IDIM_) ? s[1] : 0.f;
  float v2 = (c0 + 2 < IDIM_) ? s[2] : 0.f;
  float v3 = (c0 + 3 < IDIM_) ? s[3] : 0.f;
  uint2 pk;
  pk.x = bfbits(v0) | (bfbits(v1) << 16);
  pk.y = bfbits(v2) | (bfbits(v3) << 16);
  *reinterpret_cast<uint2*>(dst + (long)r * KPAD + c0) = pk;
}

__global__ void k_wt_convert(const float* __restrict__ src, bf16* __restrict__ dst,
                             int K, int N, int Kp) {
  int idx = blockIdx.x * 256 + threadIdx.x;
  if (idx >= N * Kp) return;
  int n = idx / Kp, kk = idx % Kp;
  dst[idx] = (kk < K) ? (bf16)src[(long)kk * N + n] : (bf16)0.f;
}

// LDS-tiled 64x64 transpose: [K,N] f32 -> [N,K] bf16
__global__ __launch_bounds__(256)
void k_wt_all(const float* __restrict__ Wq, const float* __restrict__ Wk,
              const float* __restrict__ Wv, const float* __restrict__ Wo,
              const float* __restrict__ W1, const float* __restrict__ W2,
              bf16* __restrict__ Wqkvt, bf16* __restrict__ Wot,
              bf16* __restrict__ W1t, bf16* __restrict__ W2t) {
  __shared__ float tile[64][65];
  const int s = blockIdx.y, m = s >> 2, i = s & 3;
  const float* src; bf16* dst; int K, N;
  switch (m) {
    case 0: src = Wq + (long)i*65536;  dst = Wqkvt + (long)i*196608;          K=256;  N=256;  break;
    case 1: src = Wk + (long)i*65536;  dst = Wqkvt + (long)i*196608 + 65536;  K=256;  N=256;  break;
    case 2: src = Wv + (long)i*65536;  dst = Wqkvt + (long)i*196608 + 131072; K=256;  N=256;  break;
    case 3: src = Wo + (long)i*65536;  dst = Wot + (long)i*65536;             K=256;  N=256;  break;
    case 4: src = W1 + (long)i*262144; dst = W1t + (long)i*262144;            K=256;  N=1024; break;
    default:src = W2 + (long)i*262144; dst = W2t + (long)i*262144;            K=1024; N=256;  break;
  }
  const int tiles_n = N >> 6, ntiles = (K >> 6) * tiles_n;
  if (blockIdx.x >= ntiles) return;
  const int tk = blockIdx.x / tiles_n, tn = blockIdx.x % tiles_n;
  const int t = threadIdx.x, rq = t >> 6, cl = t & 63;
  #pragma unroll
  for (int i2 = 0; i2 < 16; i2++)
    tile[rq * 16 + i2][cl] = src[(long)(tk * 64 + rq * 16 + i2) * N + tn * 64 + cl];
  __syncthreads();
  #pragma unroll
  for (int i2 = 0; i2 < 16; i2++)
    dst[(long)(tn * 64 + rq * 16 + i2) * K + tk * 64 + cl] = (bf16)tile[cl][rq * 16 + i2];
}

__global__ void k_bias_concat(const float* __restrict__ bq, const float* __restrict__ bk,
                              const float* __restrict__ bv, float* __restrict__ bqkv) {
  int idx = blockIdx.x * 256 + threadIdx.x;
  if (idx >= LL * 768) return;
  int i = idx / 768, j = idx % 768;
  float v = (j < 256) ? bq[i*256 + j] : (j < 512 ? bk[i*256 + j - 256] : bv[i*256 + j - 512]);
  bqkv[idx] = v;
}

// ---- full-row GEMM + fused bias/residual/LayerNorm (N = 256 fixed) ----
// EPI 0: write bf16 LN-output | EPI 1: write f32 LN-output (final LN)
template<int EPI>
__global__ __launch_bounds__(512, 4)
void k_gemm_row(const bf16* __restrict__ A, const bf16* __restrict__ Wt,
                const float* __restrict__ bias, const bf16* __restrict__ resid,
                const float* __restrict__ lns, const float* __restrict__ lnb,
                void* __restrict__ out, int K) {
  __shared__ alignas(16) char As[4096];
  __shared__ alignas(16) char Bs[32768];
  __shared__ alignas(16) float redS[32][4];
  __shared__ alignas(16) float redQ[32][4];
  const int t = threadIdx.x, lane = t & 63, wid = t >> 6;
  const int wr = wid >> 2, wc = wid & 3;
  const int g = lane >> 4, c = lane & 15;
  int flat = blockIdx.x;
  flat = (flat & 7) * 64 + (flat >> 3);
  const int mbase = flat * 32;

  const int srow = t >> 3;
  const int slot = ((t & 7) ^ (srow & 7)) * 8;
  const bf16* ag = A  + (long)(mbase + srow) * K + slot;
  const bf16* bg = Wt + (long)srow * K + slot;
  const int swz = (c & 7) << 4;

  f32x4 acc[4] = {};

  const int nk = K >> 6;
  for (int kt = 0; kt < nk; ++kt) {
    const int k0 = kt * 64;
    __syncthreads();
    if (wid < 4) gload_lds16(ag + k0, As + wid * 1024);
    #pragma unroll
    for (int p = 0; p < 4; p++)
      gload_lds16(bg + (long)(p * 64) * K + k0, Bs + p * 8192 + wid * 1024);
    __syncthreads();

    bf16x8 af[2], bfr[4][2];
    #pragma unroll
    for (int ks = 0; ks < 2; ks++)
      af[ks] = ld_bf8(As + (wr * 16 + c) * 128 + ((ks * 64 + g * 16) ^ swz));
    #pragma unroll
    for (int ni = 0; ni < 4; ni++)
      #pragma unroll
      for (int ks = 0; ks < 2; ks++)
        bfr[ni][ks] = ld_bf8(Bs + (wc * 64 + ni * 16 + c) * 128 + ((ks * 64 + g * 16) ^ swz));
    __builtin_amdgcn_s_setprio(1);
    #pragma unroll
    for (int ni = 0; ni < 4; ni++)
      #pragma unroll
      for (int ks = 0; ks < 2; ks++)
        acc[ni] = MFMA(af[ks], bfr[ni][ks], acc[ni]);
    __builtin_amdgcn_s_setprio(0);
  }

  float v[4][4];
  float sP[4] = {0.f, 0.f, 0.f, 0.f}, qP[4] = {0.f, 0.f, 0.f, 0.f};
  #pragma unroll
  for (int ni = 0; ni < 4; ni++) {
    const int col = wc * 64 + ni * 16 + c;
    const float bb = bias[col];
    #pragma unroll
    for (int j = 0; j < 4; j++) {
      const int row = mbase + wr * 16 + g * 4 + j;
      float r = resid ? (float)resid[(long)row * 256 + col] : 0.f;
      float x = acc[ni][j] + bb + r;
      v[ni][j] = x;
      sP[j] += x;
      qP[j] += x * x;
    }
  }
  #pragma unroll
  for (int j = 0; j < 4; j++) {
    #pragma unroll
    for (int off = 1; off < 16; off <<= 1) {
      sP[j] += __shfl_xor(sP[j], off);
      qP[j] += __shfl_xor(qP[j], off);
    }
  }
  if (c == 0) {
    #pragma unroll
    for (int j = 0; j < 4; j++) {
      const int rb = wr * 16 + g * 4 + j;
      redS[rb][wc] = sP[j];
      redQ[rb][wc] = qP[j];
    }
  }
  __syncthreads();

  #pragma unroll
  for (int j = 0; j < 4; j++) {
    const int rb = wr * 16 + g * 4 + j;
    const float4 s4 = *reinterpret_cast<const float4*>(redS[rb]);
    const float4 q4 = *reinterpret_cast<const float4*>(redQ[rb]);
    const float mean = (s4.x + s4.y + s4.z + s4.w) * (1.f / 256.f);
    const float var = (q4.x + q4.y + q4.z + q4.w) * (1.f / 256.f) - mean * mean;
    const float rstd = rsqrtf(var + EPS_);
    const long row = mbase + wr * 16 + g * 4 + j;
    #pragma unroll
    for (int ni = 0; ni < 4; ni++) {
      const int col = wc * 64 + ni * 16 + c;
      const float y = (v[ni][j] - mean) * rstd * lns[col] + lnb[col];
      if constexpr (EPI == 0) {
        ((bf16*)out)[row * 256 + col] = (bf16)y;
      } else {
        ((float*)out)[row * 256 + col] = y;
      }
    }
  }
}

// ---- fused FFN (round-13 proven body) ----
template<int EPI>
__global__ __launch_bounds__(512, 4)
void k_ffn(const bf16* __restrict__ e, const bf16* __restrict__ W1t,
           const float* __restrict__ b1, const bf16* __restrict__ W2t,
           const float* __restrict__ b2, const float* __restrict__ lns,
           const float* __restrict__ lnb, void* __restrict__ out) {
  __shared__ alignas(16) char Ae[16384];
  __shared__ alignas(16) char Hs[16384];
  __shared__ alignas(16) char Bs[32768];
  __shared__ alignas(16) float redS[32][4];
  __shared__ alignas(16) float redQ[32][4];
  const int t = threadIdx.x, lane = t & 63, wid = t >> 6;
  const int wr = wid >> 2, wc = wid & 3;
  const int g = lane >> 4, c = lane & 15;
  int flat = blockIdx.x;
  flat = (flat & 7) * 64 + (flat >> 3);
  const int mbase = flat * 32;
  const int swz = (c & 7) << 4;

  #pragma unroll
  for (int p = 0; p < 2; p++) {
    const int ch = p * 512 + t;
    const int row = ch >> 5, s = ch & 31;
    const int srcb = (s >> 3) * 128 + (((s & 7) ^ (row & 7)) << 4);
    gload_lds16(e + (long)(mbase + row) * 256 + (srcb >> 1),
                Ae + p * 8192 + wid * 1024);
  }

  const int srow = t >> 3;
  const int slot = ((t & 7) ^ (srow & 7)) * 8;
  const int arow = wr * 16 + c;
  const int axo = (arow & 7) << 4;

  f32x4 acc2[4] = {};
  asm volatile("s_waitcnt vmcnt(0)" ::: "memory");
  __builtin_amdgcn_s_barrier();

  #pragma unroll 1
  for (int q = 0; q < 4; q++) {
    f32x4 acc1[4] = {};
    const bf16* bg1 = W1t + (long)(q * 256 + srow) * 256 + slot;
    for (int kt = 0; kt < 4; ++kt) {
      __syncthreads();
      #pragma unroll
      for (int p = 0; p < 4; p++)
        gload_lds16(bg1 + (long)(p * 64) * 256 + kt * 64, Bs + p * 8192 + wid * 1024);
      __syncthreads();
      bf16x8 af[2], bfr[4][2];
      #pragma unroll
      for (int ks = 0; ks < 2; ks++)
        af[ks] = ld_bf8(Ae + arow * 512 + ((kt * 128 + ks * 64 + g * 16) ^ axo));
      #pragma unroll
      for (int ni = 0; ni < 4; ni++)
        #pragma unroll
        for (int ks = 0; ks < 2; ks++)
          bfr[ni][ks] = ld_bf8(Bs + (wc * 64 + ni * 16 + c) * 128 + ((ks * 64 + g * 16) ^ swz));
      __builtin_amdgcn_s_setprio(1);
      #pragma unroll
      for (int ni = 0; ni < 4; ni++)
        #pragma unroll
        for (int ks = 0; ks < 2; ks++)
          acc1[ni] = MFMA(af[ks], bfr[ni][ks], acc1[ni]);
      __builtin_amdgcn_s_setprio(0);
    }
    #pragma unroll
    for (int ni = 0; ni < 4; ni++) {
      const int col = wc * 64 + ni * 16 + c;
      const float bb = b1[q * 256 + col];
      #pragma unroll
      for (int j = 0; j < 4; j++) {
        const int row = wr * 16 + g * 4 + j;
        *(bf16*)(Hs + row * 512 + ((col * 2) ^ ((row & 7) << 4))) =
            (bf16)fmaxf(acc1[ni][j] + bb, 0.f);
      }
    }
    __syncthreads();
    const bf16* bg2 = W2t + (long)srow * 1024 + q * 256 + slot;
    for (int kt = 0; kt < 4; ++kt) {
      __syncthreads();
      #pragma unroll
      for (int p = 0; p < 4; p++)
        gload_lds16(bg2 + (long)(p * 64) * 1024 + kt * 64, Bs + p * 8192 + wid * 1024);
      __syncthreads();
      bf16x8 af[2], bfr[4][2];
      #pragma unroll
      for (int ks = 0; ks < 2; ks++)
        af[ks] = ld_bf8(Hs + arow * 512 + ((kt * 128 + ks * 64 + g * 16) ^ axo));
      #pragma unroll
      for (int ni = 0; ni < 4; ni++)
        #pragma unroll
        for (int ks = 0; ks < 2; ks++)
          bfr[ni][ks] = ld_bf8(Bs + (wc * 64 + ni * 16 + c) * 128 + ((ks * 64 + g * 16) ^ swz));
      __builtin_amdgcn_s_setprio(1);
      #pragma unroll
      for (int ni = 0; ni < 4; ni++)
        #pragma unroll
        for (int ks = 0; ks < 2; ks++)
          acc2[ni] = MFMA(af[ks], bfr[ni][ks], acc2[ni]);
      __builtin_amdgcn_s_setprio(0);
    }
  }

  float v[4][4];
  float sP[4] = {0.f, 0.f, 0.f, 0.f}, qP[4] = {0.f, 0.f, 0.f, 0.f};
  #pragma unroll
  for (int ni = 0; ni < 4; ni++) {
    const int col = wc * 64 + ni * 16 + c;
    const float bb = b2[col];
    #pragma unroll
    for (int j = 0; j < 4; j++) {
      const int row = wr * 16 + g * 4 + j;
      float r = (float)*(const bf16*)(Ae + row * 512 + ((col * 2) ^ ((row & 7) << 4)));
      float x = acc2[ni][j] + bb + r;
      v[ni][j] = x;
      sP[j] += x;
      qP[j] += x * x;
    }
  }
  #pragma unroll
  for (int j = 0; j < 4; j++) {
    #pragma unroll
    for (int off = 1; off < 16; off <<= 1) {
      sP[j] += __shfl_xor(sP[j], off);
      qP[j] += __shfl_xor(qP[j], off);
    }
  }
  if (c == 0) {
    #pragma unroll
    for (int j = 0; j < 4; j++) {
      const int rb = wr * 16 + g * 4 + j;
      redS[rb][wc] = sP[j];
      redQ[rb][wc] = qP[j];
    }
  }
  __syncthreads();

  #pragma unroll
  for (int j = 0; j < 4; j++) {
    const int rb = wr * 16 + g * 4 + j;
    const float4 s4 = *reinterpret_cast<const float4*>(redS[rb]);
    const float4 q4 = *reinterpret_cast<const float4*>(redQ[rb]);
    const float mean = (s4.x + s4.y + s4.z + s4.w) * (1.f / 256.f);
    const float var = (q4.x + q4.y + q4.z + q4.w) * (1.f / 256.f) - mean * mean;
    const float rstd = rsqrtf(var + EPS_);
    const long row = mbase + wr * 16 + g * 4 + j;
    #pragma unroll
    for (int ni = 0; ni < 4; ni++) {
      const int col = wc * 64 + ni * 16 + c;
      const float y = (v[ni][j] - mean) * rstd * lns[col] + lnb[col];
      if constexpr (EPI == 0) {
        ((bf16*)out)[row * 256 + col] = (bf16)y;
      } else {
        ((float*)out)[row * 256 + col] = y;
      }
    }
  }
}

// ---- GEMM 128x128 tile, BK=64, single-buffer m97 structure (QKV only) ----
template<int EPI>
__global__ __launch_bounds__(256)
void k_gemm_big(const bf16* __restrict__ A, const bf16* __restrict__ Wt,
                const float* __restrict__ bias, void* __restrict__ out,
                bf16* __restrict__ vt, int N, int K) {
  __shared__ alignas(16) char As[16384];
  __shared__ alignas(16) char Bs[16384];
  const int t = threadIdx.x, lane = t & 63, wid = t >> 6;
  const int wr = wid >> 1, wc = wid & 1;
  const int g = lane >> 4, c = lane & 15;
  int flat = blockIdx.y * gridDim.x + blockIdx.x;
  const int cpx = (gridDim.x * gridDim.y) >> 3;
  flat = (flat & 7) * cpx + (flat >> 3);
  const int mbase = (flat / gridDim.x) * 128, nbase = (flat % gridDim.x) * 128;

  const int srow = t >> 3;
  const int skc = ((t & 7) ^ (srow & 7)) * 8;
  const bf16* ag = A  + (long)(mbase + srow) * K + skc;
  const bf16* bg = Wt + (long)(nbase + srow) * K + skc;
  const int swz = (c & 7) << 4;

  f32x4 acc[4][4] = {};

  const int nk = K >> 6;
  for (int kt = 0; kt < nk; ++kt) {
    const int k0 = kt * 64;
    __syncthreads();
    #pragma unroll
    for (int p = 0; p < 4; p++) {
      gload_lds16(ag + (long)p * 32 * K + k0, As + p * 4096 + wid * 1024);
      gload_lds16(bg + (long)p * 32 * K + k0, Bs + p * 4096 + wid * 1024);
    }
    __syncthreads();

    bf16x8 af[4][2], bfr[4][2];
    #pragma unroll
    for (int mi = 0; mi < 4; mi++)
      #pragma unroll
      for (int ks = 0; ks < 2; ks++)
        af[mi][ks] = ld_bf8(As + (wr * 64 + mi * 16 + c) * 128 + ((ks * 64 + g * 16) ^ swz));
    #pragma unroll
    for (int ni = 0; ni < 4; ni++)
      #pragma unroll
      for (int ks = 0; ks < 2; ks++)
        bfr[ni][ks] = ld_bf8(Bs + (wc * 64 + ni * 16 + c) * 128 + ((ks * 64 + g * 16) ^ swz));
    __builtin_amdgcn_s_setprio(1);
    #pragma unroll
    for (int mi = 0; mi < 4; mi++)
      #pragma unroll
      for (int ni = 0; ni < 4; ni++)
        #pragma unroll
        for (int ks = 0; ks < 2; ks++)
          acc[mi][ni] = MFMA(af[mi][ks], bfr[ni][ks], acc[mi][ni]);
    __builtin_amdgcn_s_setprio(0);
  }

  #pragma unroll
  for (int mi = 0; mi < 4; mi++) {
    #pragma unroll
    for (int ni = 0; ni < 4; ni++) {
      const int colg = nbase + wc * 64 + ni * 16 + c;
      const float bv = bias ? bias[colg] : 0.f;
      if (nbase < 512) {
        const float qs = (nbase < 256) ? QSCL : 1.0f;
        #pragma unroll
        for (int j = 0; j < 4; j++) {
          const int rowg = mbase + wr * 64 + mi * 16 + g * 4 + j;
          ((bf16*)out)[(long)rowg * N + colg] = (bf16)((acc[mi][ni][j] + bv) * qs);
        }
      } else {
        const int dfull = colg - 512, hh = dfull >> 6, d = dfull & 63;
        const int rowg0 = mbase + wr * 64 + mi * 16 + g * 4;
        uint2 st;
        st.x = bfbits(acc[mi][ni][0] + bv) | (bfbits(acc[mi][ni][1] + bv) << 16);
        st.y = bfbits(acc[mi][ni][2] + bv) | (bfbits(acc[mi][ni][3] + bv) << 16);
        *reinterpret_cast<uint2*>(vt + (long)(((rowg0 >> 10) << 2) + hh) * 65536
                                     + d * 1024 + (rowg0 & 1023)) = st;
      }
    }
  }
}

// ---- flash attention: kv-ILP-2 (two kv-tiles/iter, shared Q, linear accum) ----
// 64 q-rows/block, grid 16x64 = 1024 blocks (3 blocks/CU by LDS), 8 iters.
// Fixed-shift softmax => disjoint-kv partial sums just add (no max merge).
__global__ __launch_bounds__(256)
void k_attn(const bf16* __restrict__ qkv, const bf16* __restrict__ vtg,
            bf16* __restrict__ o) {
  __shared__ alignas(16) char Ks[2][8192];   // [kv-tile A/B][64 kv][64 d] swizzled
  __shared__ alignas(16) char Vs[2][8192];
  __shared__ alignas(16) char Ps[16384];     // w*4096 + chain*2048
  const int t = threadIdx.x, lane = t & 63, w = t >> 6;
  const int g = lane >> 4, c = lane & 15;
  int flat = blockIdx.y * 16 + blockIdx.x;
  flat = (flat & 7) * 128 + (flat >> 3);     // XCD-bijective
  const int bh = flat >> 4, qt = flat & 15;
  const int b = bh >> 2, h = bh & 3;
  const long tokbase = (long)b * TT;
  const int q_glob = qt * 64 + w * 16 + c;

  bf16x8 qf0 = ld_bf8(qkv + (tokbase + q_glob) * 768 + h * 64 + g * 8);
  bf16x8 qf1 = ld_bf8(qkv + (tokbase + q_glob) * 768 + h * 64 + 32 + g * 8);

  const int sr = t >> 3;
  const int slot = (t & 7) ^ (sr & 7);
  const int swz_c = (c & 7) << 4;
  const bf16* kbase = qkv + 256 + h * 64 + slot * 8;
  const bf16* vbase = vtg + (long)bh * 65536 + slot * 8;
  char* pwA = Ps + w * 4096 + c * 128;
  char* pwB = pwA + 2048;

  f32x4 oaccA[4] = {}, oaccB[4] = {};
  float lA = 0.f, lB = 0.f;

  for (int jt = 0; jt < 8; ++jt) {
    const int jA = 2 * jt, jB = 2 * jt + 1;
    __syncthreads();   // previous iter's LDS reads complete
    gload_lds16(kbase + (tokbase + jA * 64 + sr) * 768,      Ks[0] + w * 1024);
    gload_lds16(kbase + (tokbase + jA * 64 + sr + 32) * 768, Ks[0] + 4096 + w * 1024);
    gload_lds16(kbase + (tokbase + jB * 64 + sr) * 768,      Ks[1] + w * 1024);
    gload_lds16(kbase + (tokbase + jB * 64 + sr + 32) * 768, Ks[1] + 4096 + w * 1024);
    gload_lds16(vbase + (long)sr * 1024 + jA * 64,           Vs[0] + w * 1024);
    gload_lds16(vbase + (long)(sr + 32) * 1024 + jA * 64,    Vs[0] + 4096 + w * 1024);
    gload_lds16(vbase + (long)sr * 1024 + jB * 64,           Vs[1] + w * 1024);
    gload_lds16(vbase + (long)(sr + 32) * 1024 + jB * 64,    Vs[1] + 4096 + w * 1024);
    __syncthreads();   // drain -> both tiles visible

    // QK^T both chains (shared Q fragment)
    f32x4 saccA[4] = {}, saccB[4] = {};
    __builtin_amdgcn_s_setprio(1);
    #pragma unroll
    for (int ni = 0; ni < 4; ni++) {
      const char* krA = Ks[0] + (ni * 16 + c) * 128;
      const char* krB = Ks[1] + (ni * 16 + c) * 128;
      bf16x8 kfA0 = ld_bf8(krA + ((g * 16) ^ swz_c));
      bf16x8 kfB0 = ld_bf8(krB + ((g * 16) ^ swz_c));
      bf16x8 kfA1 = ld_bf8(krA + ((64 + g * 16) ^ swz_c));
      bf16x8 kfB1 = ld_bf8(krB + ((64 + g * 16) ^ swz_c));
      saccA[ni] = MFMA(kfA0, qf0, saccA[ni]);
      saccB[ni] = MFMA(kfB0, qf0, saccB[ni]);
      saccA[ni] = MFMA(kfA1, qf1, saccA[ni]);
      saccB[ni] = MFMA(kfB1, qf1, saccB[ni]);
    }
    __builtin_amdgcn_s_setprio(0);

    // p = exp2(s - MSHIFT), two independent chains
    #pragma unroll
    for (int ni = 0; ni < 4; ni++) {
      float a0 = __builtin_amdgcn_exp2f(saccA[ni][0] - MSHIFT);
      float b0 = __builtin_amdgcn_exp2f(saccB[ni][0] - MSHIFT);
      float a1 = __builtin_amdgcn_exp2f(saccA[ni][1] - MSHIFT);
      float b1 = __builtin_amdgcn_exp2f(saccB[ni][1] - MSHIFT);
      float a2 = __builtin_amdgcn_exp2f(saccA[ni][2] - MSHIFT);
      float b2 = __builtin_amdgcn_exp2f(saccB[ni][2] - MSHIFT);
      float a3 = __builtin_amdgcn_exp2f(saccA[ni][3] - MSHIFT);
      float b3 = __builtin_amdgcn_exp2f(saccB[ni][3] - MSHIFT);
      lA += (a0 + a1) + (a2 + a3);
      lB += (b0 + b1) + (b2 + b3);
      uint2 qa, qb;
      qa.x = bfbits(a0) | (bfbits(a1) << 16);
      qa.y = bfbits(a2) | (bfbits(a3) << 16);
      qb.x = bfbits(b0) | (bfbits(b1) << 16);
      qb.y = bfbits(b2) | (bfbits(b3) << 16);
      *reinterpret_cast<uint2*>(pwA + ((ni * 32 + g * 8) ^ swz_c)) = qa;
      *reinterpret_cast<uint2*>(pwB + ((ni * 32 + g * 8) ^ swz_c)) = qb;
    }

    // PV both chains
    __builtin_amdgcn_s_setprio(1);
    #pragma unroll
    for (int kk = 0; kk < 2; kk++) {
      bf16x8 pfA = ld_bf8(pwA + ((kk * 64 + g * 16) ^ swz_c));
      bf16x8 pfB = ld_bf8(pwB + ((kk * 64 + g * 16) ^ swz_c));
      #pragma unroll
      for (int nd = 0; nd < 4; nd++) {
        bf16x8 vfA = ld_bf8(Vs[0] + (nd * 16 + c) * 128 + ((kk * 64 + g * 16) ^ swz_c));
        bf16x8 vfB = ld_bf8(Vs[1] + (nd * 16 + c) * 128 + ((kk * 64 + g * 16) ^ swz_c));
        oaccA[nd] = MFMA(vfA, pfA, oaccA[nd]);
        oaccB[nd] = MFMA(vfB, pfB, oaccB[nd]);
      }
    }
    __builtin_amdgcn_s_setprio(0);
  }

  // merge chains (disjoint kv-sets: plain add), then cross-lane reduce
  float l = lA + lB;
  l += __shfl_xor(l, 16);
  l += __shfl_xor(l, 32);
  const float inv = 1.f / l;

  bf16* orow = o + (tokbase + q_glob) * 256 + h * 64 + g * 4;
  #pragma unroll
  for (int nd = 0; nd < 4; nd++) {
    f32x4 om = oaccA[nd] + oaccB[nd];
    uint2 st;
    st.x = bfbits(om[0] * inv) | (bfbits(om[1] * inv) << 16);
    st.y = bfbits(om[2] * inv) | (bfbits(om[3] * inv) << 16);
    *reinterpret_cast<uint2*>(orow + nd * 16) = st;
  }
}

// ---- host ----
extern "C" void kernel_launch(void* const* d_in, const int* in_sizes, int n_in,
                              void* d_out, int out_size, void* d_ws, size_t ws_size,
                              hipStream_t stream) {
  const float* x     = (const float*)d_in[0];
  const float* Win   = (const float*)d_in[2];
  const float* b_in  = (const float*)d_in[3];
  const float* ln1_s = (const float*)d_in[4];
  const float* ln1_b = (const float*)d_in[5];
  const float* Wq    = (const float*)d_in[6];
  const float* bq    = (const float*)d_in[7];
  const float* Wk    = (const float*)d_in[8];
  const float* bk    = (const float*)d_in[9];
  const float* Wv    = (const float*)d_in[10];
  const float* bv    = (const float*)d_in[11];
  const float* Wo    = (const float*)d_in[12];
  const float* bo    = (const float*)d_in[13];
  const float* ln2_s = (const float*)d_in[14];
  const float* ln2_b = (const float*)d_in[15];
  const float* W1    = (const float*)d_in[16];
  const float* b1    = (const float*)d_in[17];
  const float* W2    = (const float*)d_in[18];
  const float* b2    = (const float*)d_in[19];
  const float* lno_s = (const float*)d_in[20];
  const float* lno_b = (const float*)d_in[21];
  float* out = (float*)d_out;

  char* ws = (char*)d_ws;
  size_t off = 0;
  auto alloc = [&](size_t bytes) -> void* {
    void* p = ws + off; off += (bytes + 255) & ~(size_t)255; return p;
  };
  bf16* e_bf  = (bf16*)alloc((size_t)MTOK * DD_ * 2);
  bf16* qkvb  = (bf16*)alloc((size_t)MTOK * 768 * 2);
  bf16* vtb   = (bf16*)alloc((size_t)MTOK * DD_ * 2);
  bf16* ob    = (bf16*)alloc((size_t)MTOK * DD_ * 2);
  bf16* x_bf  = (bf16*)alloc((size_t)MTOK * KPAD * 2);
  bf16* Wint  = (bf16*)alloc((size_t)DD_ * KPAD * 2);
  bf16* Wqkvt = (bf16*)alloc((size_t)LL * 768 * DD_ * 2);
  bf16* Wot   = (bf16*)alloc((size_t)LL * DD_ * DD_ * 2);
  bf16* W1t   = (bf16*)alloc((size_t)LL * DD_ * FF_ * 2);
  bf16* W2t   = (bf16*)alloc((size_t)LL * FF_ * DD_ * 2);
  float* bqkv = (float*)alloc((size_t)LL * 768 * 4);

  dim3 blk(256);

  k_convert_pad<<<(MTOK * (KPAD / 4) + 255) / 256, 256, 0, stream>>>(x, x_bf);
  k_wt_convert<<<(DD_ * KPAD + 255) / 256, 256, 0, stream>>>(Win, Wint, IDIM_, DD_, KPAD);
  k_wt_all<<<dim3(64, 24), blk, 0, stream>>>(Wq, Wk, Wv, Wo, W1, W2, Wqkvt, Wot, W1t, W2t);
  k_bias_concat<<<(LL * 768 + 255) / 256, 256, 0, stream>>>(bq, bk, bv, bqkv);

  // input projection + LN1(layer 0) fused -> e_bf
  k_gemm_row<0><<<512, 512, 0, stream>>>(x_bf, Wint, b_in, nullptr,
                                         ln1_s, ln1_b, e_bf, KPAD);

  const long DDW = (long)DD_ * DD_;
  const long DFF = (long)DD_ * FF_;
  for (int i = 0; i < LL; i++) {
    // fused QKV (q scaled, v transposed to vtb)
    k_gemm_big<3><<<dim3(6, 128), blk, 0, stream>>>(e_bf, Wqkvt + (long)i * 768 * DD_,
                                                    bqkv + i * 768, qkvb, vtb, 768, DD_);
    k_attn<<<dim3(16, 64), blk, 0, stream>>>(qkvb, vtb, ob);
    // Wo + resid(e_bf=LN1out) + LN2 fused -> e_bf
    k_gemm_row<0><<<512, 512, 0, stream>>>(ob, Wot + i * DDW, bo + i * DD_, e_bf,
                                           ln2_s + i * DD_, ln2_b + i * DD_, e_bf, DD_);
    // fused FFN (relu(e@W1+b1)@W2+b2 + resid(e)) + next-LN
    if (i < LL - 1) {
      k_ffn<0><<<512, 512, 0, stream>>>(e_bf, W1t + i * DFF, b1 + i * FF_,
                                        W2t + i * DFF, b2 + i * DD_,
                                        ln1_s + (i + 1) * DD_, ln1_b + (i + 1) * DD_, e_bf);
    } else {
      k_ffn<1><<<512, 512, 0, stream>>>(e_bf, W1t + i * DFF, b1 + i * FF_,
                                        W2t + i * DFF, b2 + i * DD_,
                                        lno_s, lno_b, out);
    }
  }
}

// Round 15
// 407.995 us; speedup vs baseline: 1.0710x; 1.0710x over previous
//
#include <hip/hip_runtime.h>
#include <hip/hip_bf16.h>

// ---- problem constants ----
#define BB    16
#define TT    1024
#define MTOK  (BB*TT)     // 16384 tokens
#define IDIM_ 345
#define KPAD  384         // padded to /64 for BK=64
#define LL    4
#define DD_   256
#define FF_   1024
#define EPS_  1e-5f
#define QSCL  0.18033688f   // 0.125 * log2(e)
#define MSHIFT 12.0f        // fixed softmax shift (scores are O(1) in log2 units)

typedef __bf16 bf16;
typedef bf16 bf16x8 __attribute__((ext_vector_type(8)));
typedef float f32x4 __attribute__((ext_vector_type(4)));

static __device__ __forceinline__ f32x4 MFMA(bf16x8 a, bf16x8 b, f32x4 c) {
  return __builtin_amdgcn_mfma_f32_16x16x32_bf16(a, b, c, 0, 0, 0);
}
static __device__ __forceinline__ unsigned bfbits(float x) {
  return (unsigned)__builtin_bit_cast(unsigned short, (bf16)x);
}
static __device__ __forceinline__ bf16x8 ld_bf8(const void* p) {
  return *reinterpret_cast<const bf16x8*>(p);
}
static __device__ __forceinline__ void gload_lds16(const bf16* g, void* l) {
  __builtin_amdgcn_global_load_lds(
      (const __attribute__((address_space(1))) void*)g,
      (__attribute__((address_space(3))) void*)l, 16, 0, 0);
}

// ---- conversion kernels ----
__global__ void k_convert_pad(const float* __restrict__ src, bf16* __restrict__ dst) {
  int idx = blockIdx.x * 256 + threadIdx.x;          // quad index
  if (idx >= MTOK * (KPAD / 4)) return;
  int r = idx / (KPAD / 4), c0 = (idx % (KPAD / 4)) * 4;
  const float* s = src + (long)r * IDIM_ + c0;
  float v0 = (c0 + 0 < IDIM_) ? s[0] : 0.f;
  float v1 = (c0 + 1 < IDIM_) ? s[1] : 0.f;
  float v2 = (c0 + 2 < IDIM_) ? s[2] : 0.f;
  float v3 = (c0 + 3 < IDIM_) ? s[3] : 0.f;
  uint2 pk;
  pk.x = bfbits(v0) | (bfbits(v1) << 16);
  pk.y = bfbits(v2) | (bfbits(v3) << 16);
  *reinterpret_cast<uint2*>(dst + (long)r * KPAD + c0) = pk;
}

__global__ void k_wt_convert(const float* __restrict__ src, bf16* __restrict__ dst,
                             int K, int N, int Kp) {
  int idx = blockIdx.x * 256 + threadIdx.x;
  if (idx >= N * Kp) return;
  int n = idx / Kp, kk = idx % Kp;
  dst[idx] = (kk < K) ? (bf16)src[(long)kk * N + n] : (bf16)0.f;
}

// LDS-tiled 64x64 transpose: [K,N] f32 -> [N,K] bf16
__global__ __launch_bounds__(256)
void k_wt_all(const float* __restrict__ Wq, const float* __restrict__ Wk,
              const float* __restrict__ Wv, const float* __restrict__ Wo,
              const float* __restrict__ W1, const float* __restrict__ W2,
              bf16* __restrict__ Wqkvt, bf16* __restrict__ Wot,
              bf16* __restrict__ W1t, bf16* __restrict__ W2t) {
  __shared__ float tile[64][65];
  const int s = blockIdx.y, m = s >> 2, i = s & 3;
  const float* src; bf16* dst; int K, N;
  switch (m) {
    case 0: src = Wq + (long)i*65536;  dst = Wqkvt + (long)i*196608;          K=256;  N=256;  break;
    case 1: src = Wk + (long)i*65536;  dst = Wqkvt + (long)i*196608 + 65536;  K=256;  N=256;  break;
    case 2: src = Wv + (long)i*65536;  dst = Wqkvt + (long)i*196608 + 131072; K=256;  N=256;  break;
    case 3: src = Wo + (long)i*65536;  dst = Wot + (long)i*65536;             K=256;  N=256;  break;
    case 4: src = W1 + (long)i*262144; dst = W1t + (long)i*262144;            K=256;  N=1024; break;
    default:src = W2 + (long)i*262144; dst = W2t + (long)i*262144;            K=1024; N=256;  break;
  }
  const int tiles_n = N >> 6, ntiles = (K >> 6) * tiles_n;
  if (blockIdx.x >= ntiles) return;
  const int tk = blockIdx.x / tiles_n, tn = blockIdx.x % tiles_n;
  const int t = threadIdx.x, rq = t >> 6, cl = t & 63;
  #pragma unroll
  for (int i2 = 0; i2 < 16; i2++)
    tile[rq * 16 + i2][cl] = src[(long)(tk * 64 + rq * 16 + i2) * N + tn * 64 + cl];
  __syncthreads();
  #pragma unroll
  for (int i2 = 0; i2 < 16; i2++)
    dst[(long)(tn * 64 + rq * 16 + i2) * K + tk * 64 + cl] = (bf16)tile[cl][rq * 16 + i2];
}

__global__ void k_bias_concat(const float* __restrict__ bq, const float* __restrict__ bk,
                              const float* __restrict__ bv, float* __restrict__ bqkv) {
  int idx = blockIdx.x * 256 + threadIdx.x;
  if (idx >= LL * 768) return;
  int i = idx / 768, j = idx % 768;
  float v = (j < 256) ? bq[i*256 + j] : (j < 512 ? bk[i*256 + j - 256] : bv[i*256 + j - 512]);
  bqkv[idx] = v;
}

// ---- full-row GEMM + fused bias/residual/LayerNorm (N = 256 fixed) ----
// EPI 0: write bf16 LN-output | EPI 1: write f32 LN-output (final LN)
template<int EPI>
__global__ __launch_bounds__(512, 4)
void k_gemm_row(const bf16* __restrict__ A, const bf16* __restrict__ Wt,
                const float* __restrict__ bias, const bf16* __restrict__ resid,
                const float* __restrict__ lns, const float* __restrict__ lnb,
                void* __restrict__ out, int K) {
  __shared__ alignas(16) char As[4096];
  __shared__ alignas(16) char Bs[32768];
  __shared__ alignas(16) float redS[32][4];
  __shared__ alignas(16) float redQ[32][4];
  const int t = threadIdx.x, lane = t & 63, wid = t >> 6;
  const int wr = wid >> 2, wc = wid & 3;
  const int g = lane >> 4, c = lane & 15;
  int flat = blockIdx.x;
  flat = (flat & 7) * 64 + (flat >> 3);
  const int mbase = flat * 32;

  const int srow = t >> 3;
  const int slot = ((t & 7) ^ (srow & 7)) * 8;
  const bf16* ag = A  + (long)(mbase + srow) * K + slot;
  const bf16* bg = Wt + (long)srow * K + slot;
  const int swz = (c & 7) << 4;

  f32x4 acc[4] = {};

  const int nk = K >> 6;
  for (int kt = 0; kt < nk; ++kt) {
    const int k0 = kt * 64;
    __syncthreads();
    if (wid < 4) gload_lds16(ag + k0, As + wid * 1024);
    #pragma unroll
    for (int p = 0; p < 4; p++)
      gload_lds16(bg + (long)(p * 64) * K + k0, Bs + p * 8192 + wid * 1024);
    __syncthreads();

    bf16x8 af[2], bfr[4][2];
    #pragma unroll
    for (int ks = 0; ks < 2; ks++)
      af[ks] = ld_bf8(As + (wr * 16 + c) * 128 + ((ks * 64 + g * 16) ^ swz));
    #pragma unroll
    for (int ni = 0; ni < 4; ni++)
      #pragma unroll
      for (int ks = 0; ks < 2; ks++)
        bfr[ni][ks] = ld_bf8(Bs + (wc * 64 + ni * 16 + c) * 128 + ((ks * 64 + g * 16) ^ swz));
    __builtin_amdgcn_s_setprio(1);
    #pragma unroll
    for (int ni = 0; ni < 4; ni++)
      #pragma unroll
      for (int ks = 0; ks < 2; ks++)
        acc[ni] = MFMA(af[ks], bfr[ni][ks], acc[ni]);
    __builtin_amdgcn_s_setprio(0);
  }

  float v[4][4];
  float sP[4] = {0.f, 0.f, 0.f, 0.f}, qP[4] = {0.f, 0.f, 0.f, 0.f};
  #pragma unroll
  for (int ni = 0; ni < 4; ni++) {
    const int col = wc * 64 + ni * 16 + c;
    const float bb = bias[col];
    #pragma unroll
    for (int j = 0; j < 4; j++) {
      const int row = mbase + wr * 16 + g * 4 + j;
      float r = resid ? (float)resid[(long)row * 256 + col] : 0.f;
      float x = acc[ni][j] + bb + r;
      v[ni][j] = x;
      sP[j] += x;
      qP[j] += x * x;
    }
  }
  #pragma unroll
  for (int j = 0; j < 4; j++) {
    #pragma unroll
    for (int off = 1; off < 16; off <<= 1) {
      sP[j] += __shfl_xor(sP[j], off);
      qP[j] += __shfl_xor(qP[j], off);
    }
  }
  if (c == 0) {
    #pragma unroll
    for (int j = 0; j < 4; j++) {
      const int rb = wr * 16 + g * 4 + j;
      redS[rb][wc] = sP[j];
      redQ[rb][wc] = qP[j];
    }
  }
  __syncthreads();

  #pragma unroll
  for (int j = 0; j < 4; j++) {
    const int rb = wr * 16 + g * 4 + j;
    const float4 s4 = *reinterpret_cast<const float4*>(redS[rb]);
    const float4 q4 = *reinterpret_cast<const float4*>(redQ[rb]);
    const float mean = (s4.x + s4.y + s4.z + s4.w) * (1.f / 256.f);
    const float var = (q4.x + q4.y + q4.z + q4.w) * (1.f / 256.f) - mean * mean;
    const float rstd = rsqrtf(var + EPS_);
    const long row = mbase + wr * 16 + g * 4 + j;
    #pragma unroll
    for (int ni = 0; ni < 4; ni++) {
      const int col = wc * 64 + ni * 16 + c;
      const float y = (v[ni][j] - mean) * rstd * lns[col] + lnb[col];
      if constexpr (EPI == 0) {
        ((bf16*)out)[row * 256 + col] = (bf16)y;
      } else {
        ((float*)out)[row * 256 + col] = y;
      }
    }
  }
}

// ---- fused FFN (round-13 proven body) ----
template<int EPI>
__global__ __launch_bounds__(512, 4)
void k_ffn(const bf16* __restrict__ e, const bf16* __restrict__ W1t,
           const float* __restrict__ b1, const bf16* __restrict__ W2t,
           const float* __restrict__ b2, const float* __restrict__ lns,
           const float* __restrict__ lnb, void* __restrict__ out) {
  __shared__ alignas(16) char Ae[16384];
  __shared__ alignas(16) char Hs[16384];
  __shared__ alignas(16) char Bs[32768];
  __shared__ alignas(16) float redS[32][4];
  __shared__ alignas(16) float redQ[32][4];
  const int t = threadIdx.x, lane = t & 63, wid = t >> 6;
  const int wr = wid >> 2, wc = wid & 3;
  const int g = lane >> 4, c = lane & 15;
  int flat = blockIdx.x;
  flat = (flat & 7) * 64 + (flat >> 3);
  const int mbase = flat * 32;
  const int swz = (c & 7) << 4;

  #pragma unroll
  for (int p = 0; p < 2; p++) {
    const int ch = p * 512 + t;
    const int row = ch >> 5, s = ch & 31;
    const int srcb = (s >> 3) * 128 + (((s & 7) ^ (row & 7)) << 4);
    gload_lds16(e + (long)(mbase + row) * 256 + (srcb >> 1),
                Ae + p * 8192 + wid * 1024);
  }

  const int srow = t >> 3;
  const int slot = ((t & 7) ^ (srow & 7)) * 8;
  const int arow = wr * 16 + c;
  const int axo = (arow & 7) << 4;

  f32x4 acc2[4] = {};
  asm volatile("s_waitcnt vmcnt(0)" ::: "memory");
  __builtin_amdgcn_s_barrier();

  #pragma unroll 1
  for (int q = 0; q < 4; q++) {
    f32x4 acc1[4] = {};
    const bf16* bg1 = W1t + (long)(q * 256 + srow) * 256 + slot;
    for (int kt = 0; kt < 4; ++kt) {
      __syncthreads();
      #pragma unroll
      for (int p = 0; p < 4; p++)
        gload_lds16(bg1 + (long)(p * 64) * 256 + kt * 64, Bs + p * 8192 + wid * 1024);
      __syncthreads();
      bf16x8 af[2], bfr[4][2];
      #pragma unroll
      for (int ks = 0; ks < 2; ks++)
        af[ks] = ld_bf8(Ae + arow * 512 + ((kt * 128 + ks * 64 + g * 16) ^ axo));
      #pragma unroll
      for (int ni = 0; ni < 4; ni++)
        #pragma unroll
        for (int ks = 0; ks < 2; ks++)
          bfr[ni][ks] = ld_bf8(Bs + (wc * 64 + ni * 16 + c) * 128 + ((ks * 64 + g * 16) ^ swz));
      __builtin_amdgcn_s_setprio(1);
      #pragma unroll
      for (int ni = 0; ni < 4; ni++)
        #pragma unroll
        for (int ks = 0; ks < 2; ks++)
          acc1[ni] = MFMA(af[ks], bfr[ni][ks], acc1[ni]);
      __builtin_amdgcn_s_setprio(0);
    }
    #pragma unroll
    for (int ni = 0; ni < 4; ni++) {
      const int col = wc * 64 + ni * 16 + c;
      const float bb = b1[q * 256 + col];
      #pragma unroll
      for (int j = 0; j < 4; j++) {
        const int row = wr * 16 + g * 4 + j;
        *(bf16*)(Hs + row * 512 + ((col * 2) ^ ((row & 7) << 4))) =
            (bf16)fmaxf(acc1[ni][j] + bb, 0.f);
      }
    }
    __syncthreads();
    const bf16* bg2 = W2t + (long)srow * 1024 + q * 256 + slot;
    for (int kt = 0; kt < 4; ++kt) {
      __syncthreads();
      #pragma unroll
      for (int p = 0; p < 4; p++)
        gload_lds16(bg2 + (long)(p * 64) * 1024 + kt * 64, Bs + p * 8192 + wid * 1024);
      __syncthreads();
      bf16x8 af[2], bfr[4][2];
      #pragma unroll
      for (int ks = 0; ks < 2; ks++)
        af[ks] = ld_bf8(Hs + arow * 512 + ((kt * 128 + ks * 64 + g * 16) ^ axo));
      #pragma unroll
      for (int ni = 0; ni < 4; ni++)
        #pragma unroll
        for (int ks = 0; ks < 2; ks++)
          bfr[ni][ks] = ld_bf8(Bs + (wc * 64 + ni * 16 + c) * 128 + ((ks * 64 + g * 16) ^ swz));
      __builtin_amdgcn_s_setprio(1);
      #pragma unroll
      for (int ni = 0; ni < 4; ni++)
        #pragma unroll
        for (int ks = 0; ks < 2; ks++)
          acc2[ni] = MFMA(af[ks], bfr[ni][ks], acc2[ni]);
      __builtin_amdgcn_s_setprio(0);
    }
  }

  float v[4][4];
  float sP[4] = {0.f, 0.f, 0.f, 0.f}, qP[4] = {0.f, 0.f, 0.f, 0.f};
  #pragma unroll
  for (int ni = 0; ni < 4; ni++) {
    const int col = wc * 64 + ni * 16 + c;
    const float bb = b2[col];
    #pragma unroll
    for (int j = 0; j < 4; j++) {
      const int row = wr * 16 + g * 4 + j;
      float r = (float)*(const bf16*)(Ae + row * 512 + ((col * 2) ^ ((row & 7) << 4)));
      float x = acc2[ni][j] + bb + r;
      v[ni][j] = x;
      sP[j] += x;
      qP[j] += x * x;
    }
  }
  #pragma unroll
  for (int j = 0; j < 4; j++) {
    #pragma unroll
    for (int off = 1; off < 16; off <<= 1) {
      sP[j] += __shfl_xor(sP[j], off);
      qP[j] += __shfl_xor(qP[j], off);
    }
  }
  if (c == 0) {
    #pragma unroll
    for (int j = 0; j < 4; j++) {
      const int rb = wr * 16 + g * 4 + j;
      redS[rb][wc] = sP[j];
      redQ[rb][wc] = qP[j];
    }
  }
  __syncthreads();

  #pragma unroll
  for (int j = 0; j < 4; j++) {
    const int rb = wr * 16 + g * 4 + j;
    const float4 s4 = *reinterpret_cast<const float4*>(redS[rb]);
    const float4 q4 = *reinterpret_cast<const float4*>(redQ[rb]);
    const float mean = (s4.x + s4.y + s4.z + s4.w) * (1.f / 256.f);
    const float var = (q4.x + q4.y + q4.z + q4.w) * (1.f / 256.f) - mean * mean;
    const float rstd = rsqrtf(var + EPS_);
    const long row = mbase + wr * 16 + g * 4 + j;
    #pragma unroll
    for (int ni = 0; ni < 4; ni++) {
      const int col = wc * 64 + ni * 16 + c;
      const float y = (v[ni][j] - mean) * rstd * lns[col] + lnb[col];
      if constexpr (EPI == 0) {
        ((bf16*)out)[row * 256 + col] = (bf16)y;
      } else {
        ((float*)out)[row * 256 + col] = y;
      }
    }
  }
}

// ---- GEMM 128x128 tile, BK=64, single-buffer m97 structure (QKV only) ----
template<int EPI>
__global__ __launch_bounds__(256)
void k_gemm_big(const bf16* __restrict__ A, const bf16* __restrict__ Wt,
                const float* __restrict__ bias, void* __restrict__ out,
                bf16* __restrict__ vt, int N, int K) {
  __shared__ alignas(16) char As[16384];
  __shared__ alignas(16) char Bs[16384];
  const int t = threadIdx.x, lane = t & 63, wid = t >> 6;
  const int wr = wid >> 1, wc = wid & 1;
  const int g = lane >> 4, c = lane & 15;
  int flat = blockIdx.y * gridDim.x + blockIdx.x;
  const int cpx = (gridDim.x * gridDim.y) >> 3;
  flat = (flat & 7) * cpx + (flat >> 3);
  const int mbase = (flat / gridDim.x) * 128, nbase = (flat % gridDim.x) * 128;

  const int srow = t >> 3;
  const int skc = ((t & 7) ^ (srow & 7)) * 8;
  const bf16* ag = A  + (long)(mbase + srow) * K + skc;
  const bf16* bg = Wt + (long)(nbase + srow) * K + skc;
  const int swz = (c & 7) << 4;

  f32x4 acc[4][4] = {};

  const int nk = K >> 6;
  for (int kt = 0; kt < nk; ++kt) {
    const int k0 = kt * 64;
    __syncthreads();
    #pragma unroll
    for (int p = 0; p < 4; p++) {
      gload_lds16(ag + (long)p * 32 * K + k0, As + p * 4096 + wid * 1024);
      gload_lds16(bg + (long)p * 32 * K + k0, Bs + p * 4096 + wid * 1024);
    }
    __syncthreads();

    bf16x8 af[4][2], bfr[4][2];
    #pragma unroll
    for (int mi = 0; mi < 4; mi++)
      #pragma unroll
      for (int ks = 0; ks < 2; ks++)
        af[mi][ks] = ld_bf8(As + (wr * 64 + mi * 16 + c) * 128 + ((ks * 64 + g * 16) ^ swz));
    #pragma unroll
    for (int ni = 0; ni < 4; ni++)
      #pragma unroll
      for (int ks = 0; ks < 2; ks++)
        bfr[ni][ks] = ld_bf8(Bs + (wc * 64 + ni * 16 + c) * 128 + ((ks * 64 + g * 16) ^ swz));
    __builtin_amdgcn_s_setprio(1);
    #pragma unroll
    for (int mi = 0; mi < 4; mi++)
      #pragma unroll
      for (int ni = 0; ni < 4; ni++)
        #pragma unroll
        for (int ks = 0; ks < 2; ks++)
          acc[mi][ni] = MFMA(af[mi][ks], bfr[ni][ks], acc[mi][ni]);
    __builtin_amdgcn_s_setprio(0);
  }

  #pragma unroll
  for (int mi = 0; mi < 4; mi++) {
    #pragma unroll
    for (int ni = 0; ni < 4; ni++) {
      const int colg = nbase + wc * 64 + ni * 16 + c;
      const float bv = bias ? bias[colg] : 0.f;
      if (nbase < 512) {
        const float qs = (nbase < 256) ? QSCL : 1.0f;
        #pragma unroll
        for (int j = 0; j < 4; j++) {
          const int rowg = mbase + wr * 64 + mi * 16 + g * 4 + j;
          ((bf16*)out)[(long)rowg * N + colg] = (bf16)((acc[mi][ni][j] + bv) * qs);
        }
      } else {
        const int dfull = colg - 512, hh = dfull >> 6, d = dfull & 63;
        const int rowg0 = mbase + wr * 64 + mi * 16 + g * 4;
        uint2 st;
        st.x = bfbits(acc[mi][ni][0] + bv) | (bfbits(acc[mi][ni][1] + bv) << 16);
        st.y = bfbits(acc[mi][ni][2] + bv) | (bfbits(acc[mi][ni][3] + bv) << 16);
        *reinterpret_cast<uint2*>(vt + (long)(((rowg0 >> 10) << 2) + hh) * 65536
                                     + d * 1024 + (rowg0 & 1023)) = st;
      }
    }
  }
}

// ---- flash attention: q-ILP-2 + dbuf KSTAGE + fixed-shift softmax ----
// (round-12/13 proven body: 39.4 us/dispatch)
__global__ __launch_bounds__(256)
void k_attn(const bf16* __restrict__ qkv, const bf16* __restrict__ vtg,
            bf16* __restrict__ o) {
  __shared__ alignas(16) char Ks[2][8192];
  __shared__ alignas(16) char Vs[2][8192];
  __shared__ alignas(16) char Ps[16384];
  const int t = threadIdx.x, lane = t & 63, w = t >> 6;
  const int g = lane >> 4, c = lane & 15;
  int flat = blockIdx.y * 8 + blockIdx.x;
  flat = (flat & 7) * 64 + (flat >> 3);
  const int bh = flat >> 3, qt = flat & 7;
  const int b = bh >> 2, h = bh & 3;
  const long tokbase = (long)b * TT;
  const int qA = qt * 128 + w * 16 + c;
  const int qB = qA + 64;

  bf16x8 qf0A = ld_bf8(qkv + (tokbase + qA) * 768 + h * 64 + g * 8);
  bf16x8 qf1A = ld_bf8(qkv + (tokbase + qA) * 768 + h * 64 + 32 + g * 8);
  bf16x8 qf0B = ld_bf8(qkv + (tokbase + qB) * 768 + h * 64 + g * 8);
  bf16x8 qf1B = ld_bf8(qkv + (tokbase + qB) * 768 + h * 64 + 32 + g * 8);

  const int sr = t >> 3;
  const int slot = (t & 7) ^ (sr & 7);
  const int swz_c = (c & 7) << 4;
  const bf16* kbase = qkv + 256 + h * 64 + slot * 8;
  const bf16* vbase = vtg + (long)bh * 65536 + slot * 8;
  char* pwA = Ps + w * 4096 + c * 128;
  char* pwB = pwA + 2048;

#define KSTAGE(bi, jt) do { \
    gload_lds16(kbase + (tokbase + (jt) * 64 + sr) * 768,      Ks[bi] + w * 1024); \
    gload_lds16(kbase + (tokbase + (jt) * 64 + sr + 32) * 768, Ks[bi] + 4096 + w * 1024); \
    gload_lds16(vbase + (long)sr * 1024 + (jt) * 64,           Vs[bi] + w * 1024); \
    gload_lds16(vbase + (long)(sr + 32) * 1024 + (jt) * 64,    Vs[bi] + 4096 + w * 1024); \
  } while (0)

  f32x4 oaccA[4] = {}, oaccB[4] = {};
  float lA = 0.f, lB = 0.f;

  KSTAGE(0, 0);
  int cur = 0;
  for (int jt = 0; jt < 16; ++jt) {
    if (jt + 1 < 16) {
      KSTAGE(cur ^ 1, jt + 1);
      asm volatile("s_waitcnt vmcnt(4)" ::: "memory");
    } else {
      asm volatile("s_waitcnt vmcnt(0)" ::: "memory");
    }
    __builtin_amdgcn_s_barrier();

    f32x4 saccA[4] = {}, saccB[4] = {};
    __builtin_amdgcn_s_setprio(1);
    #pragma unroll
    for (int ni = 0; ni < 4; ni++) {
      const char* krow = Ks[cur] + (ni * 16 + c) * 128;
      bf16x8 kf0 = ld_bf8(krow + ((g * 16) ^ swz_c));
      bf16x8 kf1 = ld_bf8(krow + ((64 + g * 16) ^ swz_c));
      saccA[ni] = MFMA(kf0, qf0A, saccA[ni]);
      saccB[ni] = MFMA(kf0, qf0B, saccB[ni]);
      saccA[ni] = MFMA(kf1, qf1A, saccA[ni]);
      saccB[ni] = MFMA(kf1, qf1B, saccB[ni]);
    }
    __builtin_amdgcn_s_setprio(0);

    #pragma unroll
    for (int ni = 0; ni < 4; ni++) {
      float a0 = __builtin_amdgcn_exp2f(saccA[ni][0] - MSHIFT);
      float b0 = __builtin_amdgcn_exp2f(saccB[ni][0] - MSHIFT);
      float a1 = __builtin_amdgcn_exp2f(saccA[ni][1] - MSHIFT);
      float b1 = __builtin_amdgcn_exp2f(saccB[ni][1] - MSHIFT);
      float a2 = __builtin_amdgcn_exp2f(saccA[ni][2] - MSHIFT);
      float b2 = __builtin_amdgcn_exp2f(saccB[ni][2] - MSHIFT);
      float a3 = __builtin_amdgcn_exp2f(saccA[ni][3] - MSHIFT);
      float b3 = __builtin_amdgcn_exp2f(saccB[ni][3] - MSHIFT);
      lA += (a0 + a1) + (a2 + a3);
      lB += (b0 + b1) + (b2 + b3);
      uint2 qa, qb;
      qa.x = bfbits(a0) | (bfbits(a1) << 16);
      qa.y = bfbits(a2) | (bfbits(a3) << 16);
      qb.x = bfbits(b0) | (bfbits(b1) << 16);
      qb.y = bfbits(b2) | (bfbits(b3) << 16);
      *reinterpret_cast<uint2*>(pwA + ((ni * 32 + g * 8) ^ swz_c)) = qa;
      *reinterpret_cast<uint2*>(pwB + ((ni * 32 + g * 8) ^ swz_c)) = qb;
    }

    __builtin_amdgcn_s_setprio(1);
    #pragma unroll
    for (int kk = 0; kk < 2; kk++) {
      bf16x8 pfA = ld_bf8(pwA + ((kk * 64 + g * 16) ^ swz_c));
      bf16x8 pfB = ld_bf8(pwB + ((kk * 64 + g * 16) ^ swz_c));
      #pragma unroll
      for (int nd = 0; nd < 4; nd++) {
        bf16x8 vf = ld_bf8(Vs[cur] + (nd * 16 + c) * 128 + ((kk * 64 + g * 16) ^ swz_c));
        oaccA[nd] = MFMA(vf, pfA, oaccA[nd]);
        oaccB[nd] = MFMA(vf, pfB, oaccB[nd]);
      }
    }
    __builtin_amdgcn_s_setprio(0);
    __builtin_amdgcn_s_barrier();
    cur ^= 1;
  }
#undef KSTAGE

  lA += __shfl_xor(lA, 16);
  lB += __shfl_xor(lB, 16);
  lA += __shfl_xor(lA, 32);
  lB += __shfl_xor(lB, 32);

  const float invA = 1.f / lA, invB = 1.f / lB;
  bf16* orowA = o + (tokbase + qA) * 256 + h * 64 + g * 4;
  bf16* orowB = o + (tokbase + qB) * 256 + h * 64 + g * 4;
  #pragma unroll
  for (int nd = 0; nd < 4; nd++) {
    uint2 sa, sb;
    sa.x = bfbits(oaccA[nd][0] * invA) | (bfbits(oaccA[nd][1] * invA) << 16);
    sa.y = bfbits(oaccA[nd][2] * invA) | (bfbits(oaccA[nd][3] * invA) << 16);
    sb.x = bfbits(oaccB[nd][0] * invB) | (bfbits(oaccB[nd][1] * invB) << 16);
    sb.y = bfbits(oaccB[nd][2] * invB) | (bfbits(oaccB[nd][3] * invB) << 16);
    *reinterpret_cast<uint2*>(orowA + nd * 16) = sa;
    *reinterpret_cast<uint2*>(orowB + nd * 16) = sb;
  }
}

// ---- host ----
extern "C" void kernel_launch(void* const* d_in, const int* in_sizes, int n_in,
                              void* d_out, int out_size, void* d_ws, size_t ws_size,
                              hipStream_t stream) {
  const float* x     = (const float*)d_in[0];
  const float* Win   = (const float*)d_in[2];
  const float* b_in  = (const float*)d_in[3];
  const float* ln1_s = (const float*)d_in[4];
  const float* ln1_b = (const float*)d_in[5];
  const float* Wq    = (const float*)d_in[6];
  const float* bq    = (const float*)d_in[7];
  const float* Wk    = (const float*)d_in[8];
  const float* bk    = (const float*)d_in[9];
  const float* Wv    = (const float*)d_in[10];
  const float* bv    = (const float*)d_in[11];
  const float* Wo    = (const float*)d_in[12];
  const float* bo    = (const float*)d_in[13];
  const float* ln2_s = (const float*)d_in[14];
  const float* ln2_b = (const float*)d_in[15];
  const float* W1    = (const float*)d_in[16];
  const float* b1    = (const float*)d_in[17];
  const float* W2    = (const float*)d_in[18];
  const float* b2    = (const float*)d_in[19];
  const float* lno_s = (const float*)d_in[20];
  const float* lno_b = (const float*)d_in[21];
  float* out = (float*)d_out;

  char* ws = (char*)d_ws;
  size_t off = 0;
  auto alloc = [&](size_t bytes) -> void* {
    void* p = ws + off; off += (bytes + 255) & ~(size_t)255; return p;
  };
  bf16* e_bf  = (bf16*)alloc((size_t)MTOK * DD_ * 2);
  bf16* qkvb  = (bf16*)alloc((size_t)MTOK * 768 * 2);
  bf16* vtb   = (bf16*)alloc((size_t)MTOK * DD_ * 2);
  bf16* ob    = (bf16*)alloc((size_t)MTOK * DD_ * 2);
  bf16* x_bf  = (bf16*)alloc((size_t)MTOK * KPAD * 2);
  bf16* Wint  = (bf16*)alloc((size_t)DD_ * KPAD * 2);
  bf16* Wqkvt = (bf16*)alloc((size_t)LL * 768 * DD_ * 2);
  bf16* Wot   = (bf16*)alloc((size_t)LL * DD_ * DD_ * 2);
  bf16* W1t   = (bf16*)alloc((size_t)LL * DD_ * FF_ * 2);
  bf16* W2t   = (bf16*)alloc((size_t)LL * FF_ * DD_ * 2);
  float* bqkv = (float*)alloc((size_t)LL * 768 * 4);

  dim3 blk(256);

  k_convert_pad<<<(MTOK * (KPAD / 4) + 255) / 256, 256, 0, stream>>>(x, x_bf);
  k_wt_convert<<<(DD_ * KPAD + 255) / 256, 256, 0, stream>>>(Win, Wint, IDIM_, DD_, KPAD);
  k_wt_all<<<dim3(64, 24), blk, 0, stream>>>(Wq, Wk, Wv, Wo, W1, W2, Wqkvt, Wot, W1t, W2t);
  k_bias_concat<<<(LL * 768 + 255) / 256, 256, 0, stream>>>(bq, bk, bv, bqkv);

  // input projection + LN1(layer 0) fused -> e_bf
  k_gemm_row<0><<<512, 512, 0, stream>>>(x_bf, Wint, b_in, nullptr,
                                         ln1_s, ln1_b, e_bf, KPAD);

  const long DDW = (long)DD_ * DD_;
  const long DFF = (long)DD_ * FF_;
  for (int i = 0; i < LL; i++) {
    // fused QKV (q scaled, v transposed to vtb)
    k_gemm_big<3><<<dim3(6, 128), blk, 0, stream>>>(e_bf, Wqkvt + (long)i * 768 * DD_,
                                                    bqkv + i * 768, qkvb, vtb, 768, DD_);
    k_attn<<<dim3(8, 64), blk, 0, stream>>>(qkvb, vtb, ob);
    // Wo + resid(e_bf=LN1out) + LN2 fused -> e_bf
    k_gemm_row<0><<<512, 512, 0, stream>>>(ob, Wot + i * DDW, bo + i * DD_, e_bf,
                                           ln2_s + i * DD_, ln2_b + i * DD_, e_bf, DD_);
    // fused FFN (relu(e@W1+b1)@W2+b2 + resid(e)) + next-LN
    if (i < LL - 1) {
      k_ffn<0><<<512, 512, 0, stream>>>(e_bf, W1t + i * DFF, b1 + i * FF_,
                                        W2t + i * DFF, b2 + i * DD_,
                                        ln1_s + (i + 1) * DD_, ln1_b + (i + 1) * DD_, e_bf);
    } else {
      k_ffn<1><<<512, 512, 0, stream>>>(e_bf, W1t + i * DFF, b1 + i * FF_,
                                        W2t + i * DFF, b2 + i * DD_,
                                        lno_s, lno_b, out);
    }
  }
}